// Round 2
// baseline (8088.247 us; speedup 1.0000x reference)
//
#include <hip/hip_runtime.h>
#include <hip/hip_bf16.h>

// ---------------------------------------------------------------------------
// GCN (3x GCNConv with COO spmm) + 3-layer dense head.  fp32 baseline.
//   h1 = tanh(spmm(x@W1) + b1)
//   h2 = tanh(spmm(h1@W2) + b2)
//   g  = spmm(h2@W3) + b3
//   d  = relu(g@Wd1+bd1); d = relu(d@Wd2+bd2); out = d@Wd3+bd3
// ---------------------------------------------------------------------------

#define BM 64
#define BN 64
#define BK 16

// ACT: 0 = none, 1 = tanh, 2 = relu
template <int ACT>
__global__ __launch_bounds__(256) void gemm_bias_act(
    const float* __restrict__ A, const float* __restrict__ B,
    const float* __restrict__ bias, float* __restrict__ C,
    int M, int K, int N) {
  __shared__ float As[BK][BM + 1];
  __shared__ float Bs[BK][BN + 1];

  const int tx = threadIdx.x & 15;   // 0..15
  const int ty = threadIdx.x >> 4;   // 0..15
  const int row0 = blockIdx.y * BM;
  const int col0 = blockIdx.x * BN;

  float acc[4][4] = {};

  for (int k0 = 0; k0 < K; k0 += BK) {
    // A tile: BM x BK (1024 elems, 4 per thread)
    #pragma unroll
    for (int i = threadIdx.x; i < BM * BK; i += 256) {
      int r = i >> 4;          // /BK
      int c = i & 15;          // %BK
      float v = 0.f;
      if (row0 + r < M && k0 + c < K) v = A[(size_t)(row0 + r) * K + k0 + c];
      As[c][r] = v;
    }
    // B tile: BK x BN
    #pragma unroll
    for (int i = threadIdx.x; i < BK * BN; i += 256) {
      int r = i >> 6;          // /BN
      int c = i & 63;          // %BN
      float v = 0.f;
      if (k0 + r < K && col0 + c < N) v = B[(size_t)(k0 + r) * N + col0 + c];
      Bs[r][c] = v;
    }
    __syncthreads();

    #pragma unroll
    for (int kk = 0; kk < BK; ++kk) {
      float a[4], b[4];
      #pragma unroll
      for (int i = 0; i < 4; ++i) a[i] = As[kk][ty * 4 + i];
      #pragma unroll
      for (int j = 0; j < 4; ++j) b[j] = Bs[kk][tx * 4 + j];
      #pragma unroll
      for (int i = 0; i < 4; ++i)
        #pragma unroll
        for (int j = 0; j < 4; ++j)
          acc[i][j] += a[i] * b[j];
    }
    __syncthreads();
  }

  #pragma unroll
  for (int i = 0; i < 4; ++i) {
    int r = row0 + ty * 4 + i;
    if (r >= M) continue;
    #pragma unroll
    for (int j = 0; j < 4; ++j) {
      int c = col0 + tx * 4 + j;
      if (c >= N) continue;
      float v = acc[i][j];
      if (bias) v += bias[c];
      if (ACT == 1) v = tanhf(v);
      else if (ACT == 2) v = fmaxf(v, 0.f);
      C[(size_t)r * N + c] = v;
    }
  }
}

// out[dst[e]] += w[e] * H[src[e]]  (atomic scatter, float4 per thread)
__global__ __launch_bounds__(256) void spmm_atomic(
    const int* __restrict__ src, const int* __restrict__ dst,
    const float* __restrict__ w, const float* __restrict__ H,
    float* __restrict__ out, int E, int F) {
  int t = blockIdx.x * 256 + threadIdx.x;
  int perEdge = F >> 2;              // float4 chunks per row
  int e = t / perEdge;
  if (e >= E) return;
  int c = (t - e * perEdge) * 4;
  int s = src[e];
  int d = dst[e];
  float wt = w[e];
  const float4 hv = *reinterpret_cast<const float4*>(&H[(size_t)s * F + c]);
  float* o = &out[(size_t)d * F + c];
  unsafeAtomicAdd(o + 0, wt * hv.x);
  unsafeAtomicAdd(o + 1, wt * hv.y);
  unsafeAtomicAdd(o + 2, wt * hv.z);
  unsafeAtomicAdd(o + 3, wt * hv.w);
}

// X[r][c] = act(X[r][c] + bias[c])  in-place
template <int ACT>
__global__ __launch_bounds__(256) void bias_act(
    float* __restrict__ X, const float* __restrict__ bias, int M, int F) {
  int t = blockIdx.x * 256 + threadIdx.x;
  if (t >= M * F) return;
  int c = t % F;
  float v = X[t] + bias[c];
  if (ACT == 1) v = tanhf(v);
  else if (ACT == 2) v = fmaxf(v, 0.f);
  X[t] = v;
}

// out[r] = dot(D2[r][:K], W[:K]) + b[0]
__global__ __launch_bounds__(256) void last_layer(
    const float* __restrict__ D2, const float* __restrict__ W,
    const float* __restrict__ b, float* __restrict__ out, int M, int K) {
  int r = blockIdx.x * 256 + threadIdx.x;
  if (r >= M) return;
  float s = b[0];
  const float* row = &D2[(size_t)r * K];
  #pragma unroll 4
  for (int k = 0; k < K; ++k) s += row[k] * W[k];
  out[r] = s;
}

extern "C" void kernel_launch(void* const* d_in, const int* in_sizes, int n_in,
                              void* d_out, int out_size, void* d_ws, size_t ws_size,
                              hipStream_t stream) {
  const int N = 20000, E = 320000;
  const int F_IN = 512, H1 = 1024, H2 = 512, F_OUT = 128;
  const int D1 = 152, D2 = 48;

  const float* x    = (const float*)d_in[0];
  const int*   src  = (const int*)d_in[1];
  const int*   dst  = (const int*)d_in[2];
  const float* ew   = (const float*)d_in[3];
  const float* W1   = (const float*)d_in[4];
  const float* b1   = (const float*)d_in[5];
  const float* W2   = (const float*)d_in[6];
  const float* b2   = (const float*)d_in[7];
  const float* W3   = (const float*)d_in[8];
  const float* b3   = (const float*)d_in[9];
  const float* Wd1  = (const float*)d_in[10];
  const float* bd1  = (const float*)d_in[11];
  const float* Wd2  = (const float*)d_in[12];
  const float* bd2  = (const float*)d_in[13];
  const float* Wd3  = (const float*)d_in[14];
  const float* bd3  = (const float*)d_in[15];
  float* out = (float*)d_out;

  // workspace layout (floats)
  float* BUF0 = (float*)d_ws;                  // 20.48M floats
  float* BUF1 = BUF0 + (size_t)N * H1;         // 20.48M floats
  float* BUF0_hi = BUF0 + (size_t)N * H2;      // second half of BUF0
  float* BUF1_hi = BUF1 + (size_t)N * F_OUT;   // g region inside BUF1

  auto cdiv = [](int a, int b) { return (a + b - 1) / b; };

  // 1. t1 = x @ W1  -> BUF0  (20000 x 1024)
  {
    dim3 g(cdiv(H1, BN), cdiv(N, BM));
    gemm_bias_act<0><<<g, 256, 0, stream>>>(x, W1, nullptr, BUF0, N, F_IN, H1);
  }
  // 2. s1 = spmm(t1) -> BUF1
  hipMemsetAsync(BUF1, 0, (size_t)N * H1 * sizeof(float), stream);
  {
    int perEdge = H1 / 4;
    long long threads = (long long)E * perEdge;
    spmm_atomic<<<(int)((threads + 255) / 256), 256, 0, stream>>>(src, dst, ew, BUF0, BUF1, E, H1);
  }
  // 3. h1 = tanh(s1 + b1) in-place
  bias_act<1><<<cdiv(N * H1, 256), 256, 0, stream>>>(BUF1, b1, N, H1);

  // 4. t2 = h1 @ W2 -> BUF0 (20000 x 512)
  {
    dim3 g(cdiv(H2, BN), cdiv(N, BM));
    gemm_bias_act<0><<<g, 256, 0, stream>>>(BUF1, W2, nullptr, BUF0, N, H1, H2);
  }
  // 5. s2 = spmm(t2) -> BUF0_hi
  hipMemsetAsync(BUF0_hi, 0, (size_t)N * H2 * sizeof(float), stream);
  {
    int perEdge = H2 / 4;
    long long threads = (long long)E * perEdge;
    spmm_atomic<<<(int)((threads + 255) / 256), 256, 0, stream>>>(src, dst, ew, BUF0, BUF0_hi, E, H2);
  }
  // 6. h2 = tanh(s2 + b2) in-place
  bias_act<1><<<cdiv(N * H2, 256), 256, 0, stream>>>(BUF0_hi, b2, N, H2);

  // 7. t3 = h2 @ W3 -> BUF1 (20000 x 128)
  {
    dim3 g(cdiv(F_OUT, BN), cdiv(N, BM));
    gemm_bias_act<0><<<g, 256, 0, stream>>>(BUF0_hi, W3, nullptr, BUF1, N, H2, F_OUT);
  }
  // 8. s3 = spmm(t3) -> BUF1_hi
  hipMemsetAsync(BUF1_hi, 0, (size_t)N * F_OUT * sizeof(float), stream);
  {
    int perEdge = F_OUT / 4;
    long long threads = (long long)E * perEdge;
    spmm_atomic<<<(int)((threads + 255) / 256), 256, 0, stream>>>(src, dst, ew, BUF1, BUF1_hi, E, F_OUT);
  }
  // 9. g = s3 + b3 in-place (no activation)
  bias_act<0><<<cdiv(N * F_OUT, 256), 256, 0, stream>>>(BUF1_hi, b3, N, F_OUT);

  // 10. d1 = relu(g @ Wd1 + bd1) -> BUF0 (20000 x 152)
  {
    dim3 g(cdiv(D1, BN), cdiv(N, BM));
    gemm_bias_act<2><<<g, 256, 0, stream>>>(BUF1_hi, Wd1, bd1, BUF0, N, F_OUT, D1);
  }
  // 11. d2 = relu(d1 @ Wd2 + bd2) -> BUF1 (20000 x 48)
  {
    dim3 g(cdiv(D2, BN), cdiv(N, BM));
    gemm_bias_act<2><<<g, 256, 0, stream>>>(BUF0, Wd2, bd2, BUF1, N, D1, D2);
  }
  // 12. out = d2 @ Wd3 + bd3
  last_layer<<<cdiv(N, 256), 256, 0, stream>>>(BUF1, Wd3, bd3, out, N, D2);
}

// Round 3
// 1535.723 us; speedup vs baseline: 5.2667x; 5.2667x over previous
//
#include <hip/hip_runtime.h>
#include <hip/hip_bf16.h>

// ---------------------------------------------------------------------------
// GCN (3x GCNConv) + 3-layer dense head.  fp32.
// Round 3: replace atomic-scatter spmm (5.24 GB HBM write-through, 4.2 ms)
// with device-built CSR + gather spmm (each output written once, gathers hit
// L3). Bias+activation fused into the spmm epilogue.
// ---------------------------------------------------------------------------

#define BM 64
#define BN 64
#define BK 16

// ACT: 0 = none, 1 = tanh, 2 = relu
template <int ACT>
__global__ __launch_bounds__(256) void gemm_bias_act(
    const float* __restrict__ A, const float* __restrict__ B,
    const float* __restrict__ bias, float* __restrict__ C,
    int M, int K, int N) {
  __shared__ float As[BK][BM + 1];
  __shared__ float Bs[BK][BN + 1];

  const int tx = threadIdx.x & 15;
  const int ty = threadIdx.x >> 4;
  const int row0 = blockIdx.y * BM;
  const int col0 = blockIdx.x * BN;

  float acc[4][4] = {};

  for (int k0 = 0; k0 < K; k0 += BK) {
    #pragma unroll
    for (int i = threadIdx.x; i < BM * BK; i += 256) {
      int r = i >> 4;
      int c = i & 15;
      float v = 0.f;
      if (row0 + r < M && k0 + c < K) v = A[(size_t)(row0 + r) * K + k0 + c];
      As[c][r] = v;
    }
    #pragma unroll
    for (int i = threadIdx.x; i < BK * BN; i += 256) {
      int r = i >> 6;
      int c = i & 63;
      float v = 0.f;
      if (k0 + r < K && col0 + c < N) v = B[(size_t)(k0 + r) * N + col0 + c];
      Bs[r][c] = v;
    }
    __syncthreads();

    #pragma unroll
    for (int kk = 0; kk < BK; ++kk) {
      float a[4], b[4];
      #pragma unroll
      for (int i = 0; i < 4; ++i) a[i] = As[kk][ty * 4 + i];
      #pragma unroll
      for (int j = 0; j < 4; ++j) b[j] = Bs[kk][tx * 4 + j];
      #pragma unroll
      for (int i = 0; i < 4; ++i)
        #pragma unroll
        for (int j = 0; j < 4; ++j)
          acc[i][j] += a[i] * b[j];
    }
    __syncthreads();
  }

  #pragma unroll
  for (int i = 0; i < 4; ++i) {
    int r = row0 + ty * 4 + i;
    if (r >= M) continue;
    #pragma unroll
    for (int j = 0; j < 4; ++j) {
      int c = col0 + tx * 4 + j;
      if (c >= N) continue;
      float v = acc[i][j];
      if (bias) v += bias[c];
      if (ACT == 1) v = tanhf(v);
      else if (ACT == 2) v = fmaxf(v, 0.f);
      C[(size_t)r * N + c] = v;
    }
  }
}

// ---------------- CSR build (per call; deterministic work) ------------------

__global__ __launch_bounds__(256) void count_deg(
    const int* __restrict__ dst, int* __restrict__ cnt, int E) {
  int e = blockIdx.x * 256 + threadIdx.x;
  if (e < E) atomicAdd(&cnt[dst[e]], 1);
}

// single-block exclusive scan of n values (+ total at out[n])
__global__ __launch_bounds__(1024) void exscan_kernel(
    const int* __restrict__ in, int* __restrict__ out, int n) {
  __shared__ int buf[2][1024];
  __shared__ int carry;
  if (threadIdx.x == 0) carry = 0;
  __syncthreads();
  for (int base = 0; base < n; base += 1024) {
    int i = base + threadIdx.x;
    int v = (i < n) ? in[i] : 0;
    int cur = 0;
    buf[0][threadIdx.x] = v;
    __syncthreads();
    #pragma unroll
    for (int off = 1; off < 1024; off <<= 1) {
      int val = buf[cur][threadIdx.x];
      if (threadIdx.x >= off) val += buf[cur][threadIdx.x - off];
      buf[cur ^ 1][threadIdx.x] = val;
      cur ^= 1;
      __syncthreads();
    }
    int incl = buf[cur][threadIdx.x];
    if (i < n) out[i] = carry + incl - v;   // exclusive
    __syncthreads();
    if (threadIdx.x == 0) carry += buf[cur][1023];
    __syncthreads();
  }
  if (threadIdx.x == 0) out[n] = carry;
}

__global__ __launch_bounds__(256) void scatter_perm(
    const int* __restrict__ dst, const int* __restrict__ row_ptr,
    int* __restrict__ cnt, int* __restrict__ perm, int E) {
  int e = blockIdx.x * 256 + threadIdx.x;
  if (e >= E) return;
  int d = dst[e];
  int pos = row_ptr[d] + atomicAdd(&cnt[d], 1);
  perm[pos] = e;
}

// ------------------------- gather spmm (no atomics) -------------------------
// out[i][c] = act( sum_{p in row i} w[perm[p]] * H[src[perm[p]]][c] + bias[c] )
template <int ACT>
__global__ __launch_bounds__(256) void spmm_csr(
    const int* __restrict__ row_ptr, const int* __restrict__ perm,
    const int* __restrict__ src, const float* __restrict__ w,
    const float* __restrict__ H, const float* __restrict__ bias,
    float* __restrict__ out, int N, int F) {
  int t = blockIdx.x * 256 + threadIdx.x;
  int chunks = F >> 2;
  int node = t / chunks;
  if (node >= N) return;
  int c = (t - node * chunks) * 4;

  int beg = row_ptr[node];
  int end = row_ptr[node + 1];
  float4 acc = {0.f, 0.f, 0.f, 0.f};
  for (int p = beg; p < end; ++p) {
    int e = perm[p];
    int s = src[e];
    float wt = w[e];
    const float4 hv = *reinterpret_cast<const float4*>(&H[(size_t)s * F + c]);
    acc.x += wt * hv.x;
    acc.y += wt * hv.y;
    acc.z += wt * hv.z;
    acc.w += wt * hv.w;
  }
  if (bias) {
    acc.x += bias[c + 0];
    acc.y += bias[c + 1];
    acc.z += bias[c + 2];
    acc.w += bias[c + 3];
  }
  if (ACT == 1) {
    acc.x = tanhf(acc.x); acc.y = tanhf(acc.y);
    acc.z = tanhf(acc.z); acc.w = tanhf(acc.w);
  } else if (ACT == 2) {
    acc.x = fmaxf(acc.x, 0.f); acc.y = fmaxf(acc.y, 0.f);
    acc.z = fmaxf(acc.z, 0.f); acc.w = fmaxf(acc.w, 0.f);
  }
  *reinterpret_cast<float4*>(&out[(size_t)node * F + c]) = acc;
}

// out[r] = dot(D2[r][:K], W[:K]) + b[0]
__global__ __launch_bounds__(256) void last_layer(
    const float* __restrict__ D2, const float* __restrict__ W,
    const float* __restrict__ b, float* __restrict__ out, int M, int K) {
  int r = blockIdx.x * 256 + threadIdx.x;
  if (r >= M) return;
  float s = b[0];
  const float* row = &D2[(size_t)r * K];
  #pragma unroll 4
  for (int k = 0; k < K; ++k) s += row[k] * W[k];
  out[r] = s;
}

extern "C" void kernel_launch(void* const* d_in, const int* in_sizes, int n_in,
                              void* d_out, int out_size, void* d_ws, size_t ws_size,
                              hipStream_t stream) {
  const int N = 20000, E = 320000;
  const int F_IN = 512, H1 = 1024, H2 = 512, F_OUT = 128;
  const int D1 = 152, D2 = 48;

  const float* x    = (const float*)d_in[0];
  const int*   src  = (const int*)d_in[1];
  const int*   dst  = (const int*)d_in[2];
  const float* ew   = (const float*)d_in[3];
  const float* W1   = (const float*)d_in[4];
  const float* b1   = (const float*)d_in[5];
  const float* W2   = (const float*)d_in[6];
  const float* b2   = (const float*)d_in[7];
  const float* W3   = (const float*)d_in[8];
  const float* b3   = (const float*)d_in[9];
  const float* Wd1  = (const float*)d_in[10];
  const float* bd1  = (const float*)d_in[11];
  const float* Wd2  = (const float*)d_in[12];
  const float* bd2  = (const float*)d_in[13];
  const float* Wd3  = (const float*)d_in[14];
  const float* bd3  = (const float*)d_in[15];
  float* out = (float*)d_out;

  // workspace layout:
  //   BUF0, BUF1: N*H1 floats each (82 MB each)
  //   CSR block (row_ptr[N+1], cnt[N], perm[E]) at the END of ws (1.44 MB)
  float* BUF0 = (float*)d_ws;
  float* BUF1 = BUF0 + (size_t)N * H1;
  float* BUF0_hi = BUF0 + (size_t)N * H2;
  float* BUF1_hi = BUF1 + (size_t)N * F_OUT;

  size_t csr_ints = (size_t)(N + 1) + N + E;
  int* csr_base = (int*)(((uintptr_t)d_ws + ws_size - csr_ints * sizeof(int)) & ~(uintptr_t)15);
  int* row_ptr = csr_base;          // N+1
  int* cnt     = row_ptr + (N + 1); // N
  int* perm    = cnt + N;           // E

  auto cdiv = [](int a, int b) { return (a + b - 1) / b; };

  // ---- CSR build (by destination) ----
  hipMemsetAsync(cnt, 0, (size_t)N * sizeof(int), stream);
  count_deg<<<cdiv(E, 256), 256, 0, stream>>>(dst, cnt, E);
  exscan_kernel<<<1, 1024, 0, stream>>>(cnt, row_ptr, N);
  hipMemsetAsync(cnt, 0, (size_t)N * sizeof(int), stream);
  scatter_perm<<<cdiv(E, 256), 256, 0, stream>>>(dst, row_ptr, cnt, perm, E);

  // ---- layer 1: h1 = tanh(spmm(x@W1) + b1) ----
  {
    dim3 g(cdiv(H1, BN), cdiv(N, BM));
    gemm_bias_act<0><<<g, 256, 0, stream>>>(x, W1, nullptr, BUF0, N, F_IN, H1);
  }
  {
    int total = N * (H1 >> 2);
    spmm_csr<1><<<cdiv(total, 256), 256, 0, stream>>>(row_ptr, perm, src, ew,
                                                      BUF0, b1, BUF1, N, H1);
  }

  // ---- layer 2: h2 = tanh(spmm(h1@W2) + b2) ----
  {
    dim3 g(cdiv(H2, BN), cdiv(N, BM));
    gemm_bias_act<0><<<g, 256, 0, stream>>>(BUF1, W2, nullptr, BUF0, N, H1, H2);
  }
  {
    int total = N * (H2 >> 2);
    spmm_csr<1><<<cdiv(total, 256), 256, 0, stream>>>(row_ptr, perm, src, ew,
                                                      BUF0, b2, BUF0_hi, N, H2);
  }

  // ---- layer 3: g = spmm(h2@W3) + b3 ----
  {
    dim3 g(cdiv(F_OUT, BN), cdiv(N, BM));
    gemm_bias_act<0><<<g, 256, 0, stream>>>(BUF0_hi, W3, nullptr, BUF1, N, H2, F_OUT);
  }
  {
    int total = N * (F_OUT >> 2);
    spmm_csr<0><<<cdiv(total, 256), 256, 0, stream>>>(row_ptr, perm, src, ew,
                                                      BUF1, b3, BUF1_hi, N, F_OUT);
  }

  // ---- dense head ----
  {
    dim3 g(cdiv(D1, BN), cdiv(N, BM));
    gemm_bias_act<2><<<g, 256, 0, stream>>>(BUF1_hi, Wd1, bd1, BUF0, N, F_OUT, D1);
  }
  {
    dim3 g(cdiv(D2, BN), cdiv(N, BM));
    gemm_bias_act<2><<<g, 256, 0, stream>>>(BUF0, Wd2, bd2, BUF1, N, D1, D2);
  }
  last_layer<<<cdiv(N, 256), 256, 0, stream>>>(BUF1, Wd3, bd3, out, N, D2);
}

// Round 4
// 475.348 us; speedup vs baseline: 17.0154x; 3.2307x over previous
//
#include <hip/hip_runtime.h>
#include <hip/hip_bf16.h>

// ---------------------------------------------------------------------------
// GCN (3x GCNConv) + dense head.
// Round 4: bf16 MFMA GEMMs (m97 structure: 128x128 tile, BK=64,
// global_load_lds w=16, XOR-swizzled LDS via pre-swizzled source),
// block-per-node gather spmm reading bf16, fp32 dense head.
// ---------------------------------------------------------------------------

typedef __attribute__((ext_vector_type(8))) short bf16x8;
typedef __attribute__((ext_vector_type(4))) float f32x4;
typedef unsigned short u16;

#define MPAD 20096   // 20000 padded to multiple of 128

__device__ inline u16 f2b(float f) {
  union { float f; unsigned int u; } x; x.f = f;
  unsigned int r = x.u + 0x7FFFu + ((x.u >> 16) & 1u);   // RNE
  return (u16)(r >> 16);
}
__device__ inline float b2f(u16 u) {
  union { unsigned int u; float f; } x; x.u = ((unsigned int)u) << 16; return x.f;
}

// ----------------------- conversion kernels --------------------------------

// x fp32 [M x K] -> xb bf16 [MPAD x K], pad rows zeroed
__global__ __launch_bounds__(256) void cvt_x(
    const float* __restrict__ in, u16* __restrict__ out, int M, int K) {
  int idx = (blockIdx.x * 256 + threadIdx.x) * 4;
  if (idx >= MPAD * K) return;
  int r = idx / K;
  float4 v = make_float4(0.f, 0.f, 0.f, 0.f);
  if (r < M) v = *reinterpret_cast<const float4*>(&in[idx]);
  ushort4 o;
  o.x = f2b(v.x); o.y = f2b(v.y); o.z = f2b(v.z); o.w = f2b(v.w);
  *reinterpret_cast<ushort4*>(&out[idx]) = o;
}

// W fp32 [K x N] -> WT bf16 [N x K]
__global__ __launch_bounds__(256) void cvt_wT(
    const float* __restrict__ W, u16* __restrict__ WT, int K, int N) {
  int t = blockIdx.x * 256 + threadIdx.x;
  if (t >= K * N) return;
  int n = t / K, k = t - n * K;
  WT[t] = f2b(W[(size_t)k * N + n]);
}

// ----------------------- CSR build -----------------------------------------

__global__ __launch_bounds__(256) void count_deg(
    const int* __restrict__ dst, int* __restrict__ cnt, int E) {
  int e = blockIdx.x * 256 + threadIdx.x;
  if (e < E) atomicAdd(&cnt[dst[e]], 1);
}

__global__ __launch_bounds__(1024) void exscan_kernel(
    const int* __restrict__ in, int* __restrict__ out, int n) {
  __shared__ int buf[2][1024];
  __shared__ int carry;
  if (threadIdx.x == 0) carry = 0;
  __syncthreads();
  for (int base = 0; base < n; base += 1024) {
    int i = base + threadIdx.x;
    int v = (i < n) ? in[i] : 0;
    int cur = 0;
    buf[0][threadIdx.x] = v;
    __syncthreads();
    #pragma unroll
    for (int off = 1; off < 1024; off <<= 1) {
      int val = buf[cur][threadIdx.x];
      if (threadIdx.x >= off) val += buf[cur][threadIdx.x - off];
      buf[cur ^ 1][threadIdx.x] = val;
      cur ^= 1;
      __syncthreads();
    }
    int incl = buf[cur][threadIdx.x];
    if (i < n) out[i] = carry + incl - v;
    __syncthreads();
    if (threadIdx.x == 0) carry += buf[cur][1023];
    __syncthreads();
  }
  if (threadIdx.x == 0) out[n] = carry;
}

// materialize permuted src/w so spmm has no perm indirection
__global__ __launch_bounds__(256) void scatter_csr(
    const int* __restrict__ dst, const int* __restrict__ src,
    const float* __restrict__ ew, const int* __restrict__ row_ptr,
    int* __restrict__ cnt, int* __restrict__ csr_src,
    float* __restrict__ csr_w, int E) {
  int e = blockIdx.x * 256 + threadIdx.x;
  if (e >= E) return;
  int d = dst[e];
  int pos = row_ptr[d] + atomicAdd(&cnt[d], 1);
  csr_src[pos] = src[e];
  csr_w[pos] = ew[e];
}

// ----------------------- bf16 MFMA GEMM ------------------------------------
// C[M x Nn] = A[M x K] @ B  with BT[Nn x K] given (both bf16 row-major).
// M multiple of 128 (padded), Nn multiple of 128, K multiple of 64.
// 128x128 tile, BK=64, 4 waves each computing 64x64.
// LDS XOR swizzle: ushort index ^= (row&7)<<3, applied on read; staging keeps
// LDS linear and pre-swizzles the GLOBAL source (rule 21 / m201 pattern).
template <bool OUT_BF16>
__global__ __launch_bounds__(256) void gemm_mfma_bf16(
    const u16* __restrict__ A, const u16* __restrict__ BT,
    void* __restrict__ C, int M, int K, int Nn) {
  __shared__ __align__(16) u16 As[128 * 64];
  __shared__ __align__(16) u16 Bs[128 * 64];
  const int tid = threadIdx.x;
  const int lane = tid & 63;
  const int wave = tid >> 6;
  const int lo = lane & 15, hi = lane >> 4;
  const int wr = wave >> 1, wc = wave & 1;
  const int row0 = blockIdx.y * 128;
  const int col0 = blockIdx.x * 128;

  f32x4 acc[4][4] = {};

  for (int kt = 0; kt < K; kt += 64) {
    __syncthreads();
    #pragma unroll
    for (int i = 0; i < 4; ++i) {
      int o = i * 4096 + tid * 16;        // linear byte offset in 16KB tile
      int r = o >> 7;                      // tile row
      int kb = o & 127;                    // byte within row
      int ke = (kb >> 1) ^ ((r & 7) << 3); // pre-swizzled element within row
      const u16* ga = &A[(size_t)(row0 + r) * K + kt + ke];
      const u16* gb = &BT[(size_t)(col0 + r) * K + kt + ke];
      __builtin_amdgcn_global_load_lds(
          (const __attribute__((address_space(1))) void*)ga,
          (__attribute__((address_space(3))) void*)&As[o >> 1], 16, 0, 0);
      __builtin_amdgcn_global_load_lds(
          (const __attribute__((address_space(1))) void*)gb,
          (__attribute__((address_space(3))) void*)&Bs[o >> 1], 16, 0, 0);
    }
    __syncthreads();

    #pragma unroll
    for (int ks = 0; ks < 2; ++ks) {
      bf16x8 af[4], bfr[4];
      #pragma unroll
      for (int m = 0; m < 4; ++m) {
        int row = wr * 64 + m * 16 + lo;
        int idx = (row * 64 + ks * 32 + hi * 8) ^ ((row & 7) << 3);
        af[m] = *reinterpret_cast<const bf16x8*>(&As[idx]);
      }
      #pragma unroll
      for (int n = 0; n < 4; ++n) {
        int col = wc * 64 + n * 16 + lo;
        int idx = (col * 64 + ks * 32 + hi * 8) ^ ((col & 7) << 3);
        bfr[n] = *reinterpret_cast<const bf16x8*>(&Bs[idx]);
      }
      #pragma unroll
      for (int m = 0; m < 4; ++m)
        #pragma unroll
        for (int n = 0; n < 4; ++n)
          acc[m][n] = __builtin_amdgcn_mfma_f32_16x16x32_bf16(
              af[m], bfr[n], acc[m][n], 0, 0, 0);
    }
  }

  // epilogue: D mapping col=lane&15, row=(lane>>4)*4+i
  u16* Cb = (u16*)C;
  float* Cf = (float*)C;
  #pragma unroll
  for (int m = 0; m < 4; ++m) {
    int rbase = row0 + wr * 64 + m * 16 + hi * 4;
    #pragma unroll
    for (int n = 0; n < 4; ++n) {
      int c = col0 + wc * 64 + n * 16 + lo;
      #pragma unroll
      for (int i = 0; i < 4; ++i) {
        float v = acc[m][n][i];
        size_t off = (size_t)(rbase + i) * Nn + c;
        if (OUT_BF16) Cb[off] = f2b(v);
        else Cf[off] = v;
      }
    }
  }
}

// ----------------------- gather spmm ---------------------------------------
// out[i][:] = act( sum_p csr_w[p] * H[csr_src[p]][:] + bias )  (H is bf16)
// ACT: 0=none, 1=tanh.  OUT_BF16 selects output dtype.
template <int F, int ACT, bool OUT_BF16>
__global__ __launch_bounds__(256) void spmm_gather(
    const int* __restrict__ row_ptr, const int* __restrict__ csr_src,
    const float* __restrict__ csr_w, const u16* __restrict__ H,
    const float* __restrict__ bias, void* __restrict__ out, int N) {
  constexpr int TPN = F / 4;          // threads per node (4 cols each)
  constexpr int NPB = 256 / TPN;      // nodes per block
  int sub = threadIdx.x / TPN;
  int ln = threadIdx.x - sub * TPN;
  int node = blockIdx.x * NPB + sub;
  if (node >= N) return;
  int c = ln * 4;
  int beg = row_ptr[node], end = row_ptr[node + 1];
  float a0 = 0.f, a1 = 0.f, a2 = 0.f, a3 = 0.f;
  for (int p = beg; p < end; ++p) {
    int s = csr_src[p];
    float wt = csr_w[p];
    ushort4 hv = *reinterpret_cast<const ushort4*>(&H[(size_t)s * F + c]);
    a0 += wt * b2f(hv.x);
    a1 += wt * b2f(hv.y);
    a2 += wt * b2f(hv.z);
    a3 += wt * b2f(hv.w);
  }
  a0 += bias[c + 0]; a1 += bias[c + 1]; a2 += bias[c + 2]; a3 += bias[c + 3];
  if (ACT == 1) { a0 = tanhf(a0); a1 = tanhf(a1); a2 = tanhf(a2); a3 = tanhf(a3); }
  if (OUT_BF16) {
    ushort4 o; o.x = f2b(a0); o.y = f2b(a1); o.z = f2b(a2); o.w = f2b(a3);
    *reinterpret_cast<ushort4*>(&((u16*)out)[(size_t)node * F + c]) = o;
  } else {
    float4 o = make_float4(a0, a1, a2, a3);
    *reinterpret_cast<float4*>(&((float*)out)[(size_t)node * F + c]) = o;
  }
}

// ----------------------- fp32 dense head -----------------------------------

#define BM 64
#define BN 64
#define BK 16

template <int ACT>   // 0=none, 1=tanh, 2=relu
__global__ __launch_bounds__(256) void gemm_bias_act(
    const float* __restrict__ A, const float* __restrict__ B,
    const float* __restrict__ bias, float* __restrict__ C,
    int M, int K, int N) {
  __shared__ float As[BK][BM + 1];
  __shared__ float Bs[BK][BN + 1];
  const int tx = threadIdx.x & 15;
  const int ty = threadIdx.x >> 4;
  const int row0 = blockIdx.y * BM;
  const int col0 = blockIdx.x * BN;
  float acc[4][4] = {};
  for (int k0 = 0; k0 < K; k0 += BK) {
    #pragma unroll
    for (int i = threadIdx.x; i < BM * BK; i += 256) {
      int r = i >> 4, c = i & 15;
      float v = 0.f;
      if (row0 + r < M && k0 + c < K) v = A[(size_t)(row0 + r) * K + k0 + c];
      As[c][r] = v;
    }
    #pragma unroll
    for (int i = threadIdx.x; i < BK * BN; i += 256) {
      int r = i >> 6, c = i & 63;
      float v = 0.f;
      if (k0 + r < K && col0 + c < N) v = B[(size_t)(k0 + r) * N + col0 + c];
      Bs[r][c] = v;
    }
    __syncthreads();
    #pragma unroll
    for (int kk = 0; kk < BK; ++kk) {
      float a[4], b[4];
      #pragma unroll
      for (int i = 0; i < 4; ++i) a[i] = As[kk][ty * 4 + i];
      #pragma unroll
      for (int j = 0; j < 4; ++j) b[j] = Bs[kk][tx * 4 + j];
      #pragma unroll
      for (int i = 0; i < 4; ++i)
        #pragma unroll
        for (int j = 0; j < 4; ++j)
          acc[i][j] += a[i] * b[j];
    }
    __syncthreads();
  }
  #pragma unroll
  for (int i = 0; i < 4; ++i) {
    int r = row0 + ty * 4 + i;
    if (r >= M) continue;
    #pragma unroll
    for (int j = 0; j < 4; ++j) {
      int c = col0 + tx * 4 + j;
      if (c >= N) continue;
      float v = acc[i][j];
      if (bias) v += bias[c];
      if (ACT == 1) v = tanhf(v);
      else if (ACT == 2) v = fmaxf(v, 0.f);
      C[(size_t)r * N + c] = v;
    }
  }
}

__global__ __launch_bounds__(256) void last_layer(
    const float* __restrict__ D2v, const float* __restrict__ W,
    const float* __restrict__ b, float* __restrict__ out, int M, int K) {
  int r = blockIdx.x * 256 + threadIdx.x;
  if (r >= M) return;
  float s = b[0];
  const float* row = &D2v[(size_t)r * K];
  #pragma unroll 4
  for (int k = 0; k < K; ++k) s += row[k] * W[k];
  out[r] = s;
}

// ---------------------------------------------------------------------------

extern "C" void kernel_launch(void* const* d_in, const int* in_sizes, int n_in,
                              void* d_out, int out_size, void* d_ws, size_t ws_size,
                              hipStream_t stream) {
  const int N = 20000, E = 320000;
  const int F_IN = 512, H1 = 1024, H2 = 512, F_OUT = 128;
  const int D1 = 152, D2 = 48;

  const float* x    = (const float*)d_in[0];
  const int*   src  = (const int*)d_in[1];
  const int*   dst  = (const int*)d_in[2];
  const float* ew   = (const float*)d_in[3];
  const float* W1   = (const float*)d_in[4];
  const float* b1   = (const float*)d_in[5];
  const float* W2   = (const float*)d_in[6];
  const float* b2   = (const float*)d_in[7];
  const float* W3   = (const float*)d_in[8];
  const float* b3   = (const float*)d_in[9];
  const float* Wd1  = (const float*)d_in[10];
  const float* bd1  = (const float*)d_in[11];
  const float* Wd2  = (const float*)d_in[12];
  const float* bd2  = (const float*)d_in[13];
  const float* Wd3  = (const float*)d_in[14];
  const float* bd3  = (const float*)d_in[15];
  float* out = (float*)d_out;

  // ---- workspace layout (bump allocation, 256B aligned) ----
  size_t off = 0;
  auto alloc = [&](size_t bytes) {
    void* p = (char*)d_ws + off;
    off += (bytes + 255) & ~(size_t)255;
    return p;
  };
  u16* xb  = (u16*)alloc((size_t)MPAD * F_IN * 2);      // also t2
  u16* t1  = (u16*)alloc((size_t)MPAD * H1 * 2);        // also h2, t3
  u16* h1  = (u16*)alloc((size_t)MPAD * H1 * 2);        // also g, d1, d2
  u16* w1t = (u16*)alloc((size_t)H1 * F_IN * 2);
  u16* w2t = (u16*)alloc((size_t)H2 * H1 * 2);
  u16* w3t = (u16*)alloc((size_t)F_OUT * H2 * 2);
  int* row_ptr = (int*)alloc((size_t)(N + 1) * 4);
  int* cnt     = (int*)alloc((size_t)N * 4);
  int* csr_src = (int*)alloc((size_t)E * 4);
  float* csr_w = (float*)alloc((size_t)E * 4);

  u16* t2 = xb;                                  // MPAD x 512
  u16* h2 = t1;                                  // MPAD x 512
  u16* t3 = t1 + (size_t)MPAD * H2;              // MPAD x 128
  float* g  = (float*)h1;                        // 20000 x 128 fp32
  float* d1 = (float*)((char*)h1 + 10240000);    // 20000 x 152 fp32
  float* d2 = (float*)((char*)h1 + 22400000);    // 20000 x 48 fp32

  auto cdiv = [](int a, int b) { return (a + b - 1) / b; };

  // ---- conversions ----
  cvt_x<<<cdiv(MPAD * F_IN / 4, 256), 256, 0, stream>>>(x, xb, N, F_IN);
  cvt_wT<<<cdiv(F_IN * H1, 256), 256, 0, stream>>>(W1, w1t, F_IN, H1);
  cvt_wT<<<cdiv(H1 * H2, 256), 256, 0, stream>>>(W2, w2t, H1, H2);
  cvt_wT<<<cdiv(H2 * F_OUT, 256), 256, 0, stream>>>(W3, w3t, H2, F_OUT);

  // ---- CSR build ----
  hipMemsetAsync(cnt, 0, (size_t)N * 4, stream);
  count_deg<<<cdiv(E, 256), 256, 0, stream>>>(dst, cnt, E);
  exscan_kernel<<<1, 1024, 0, stream>>>(cnt, row_ptr, N);
  hipMemsetAsync(cnt, 0, (size_t)N * 4, stream);
  scatter_csr<<<cdiv(E, 256), 256, 0, stream>>>(dst, src, ew, row_ptr, cnt,
                                                csr_src, csr_w, E);

  // ---- layer 1 ----
  {
    dim3 gr(H1 / 128, MPAD / 128);
    gemm_mfma_bf16<true><<<gr, 256, 0, stream>>>(xb, w1t, t1, MPAD, F_IN, H1);
  }
  spmm_gather<1024, 1, true><<<N, 256, 0, stream>>>(row_ptr, csr_src, csr_w,
                                                    t1, b1, h1, N);
  // ---- layer 2 ----
  {
    dim3 gr(H2 / 128, MPAD / 128);
    gemm_mfma_bf16<true><<<gr, 256, 0, stream>>>(h1, w2t, t2, MPAD, H1, H2);
  }
  spmm_gather<512, 1, true><<<cdiv(N, 2), 256, 0, stream>>>(row_ptr, csr_src,
                                                            csr_w, t2, b2, h2, N);
  // ---- layer 3 ----
  {
    dim3 gr(F_OUT / 128, MPAD / 128);
    gemm_mfma_bf16<true><<<gr, 256, 0, stream>>>(h2, w3t, t3, MPAD, H2, F_OUT);
  }
  spmm_gather<128, 0, false><<<cdiv(N, 8), 256, 0, stream>>>(row_ptr, csr_src,
                                                             csr_w, t3, b3, g, N);
  // ---- dense head (fp32) ----
  {
    dim3 gr(cdiv(D1, BN), cdiv(N, BM));
    gemm_bias_act<2><<<gr, 256, 0, stream>>>(g, Wd1, bd1, d1, N, F_OUT, D1);
  }
  {
    dim3 gr(cdiv(D2, BN), cdiv(N, BM));
    gemm_bias_act<2><<<gr, 256, 0, stream>>>(d1, Wd2, bd2, d2, N, D1, D2);
  }
  last_layer<<<cdiv(N, 256), 256, 0, stream>>>(d2, Wd3, bd3, out, N, D2);
}

// Round 5
// 369.691 us; speedup vs baseline: 21.8784x; 1.2858x over previous
//
#include <hip/hip_runtime.h>
#include <hip/hip_bf16.h>

// ---------------------------------------------------------------------------
// GCN (3x GCNConv) + dense head.
// Round 5: algebraic reorder of layer 1 (spmm(x)@W1 instead of spmm(x@W1)):
// spmm moves from F=1024 to F=512 (halves gather bytes). Wave-per-node spmm
// with LDS-staged edge lists (kills redundant index loads), ushort8 gathers.
// Bias+tanh for layer 1 fused into the MFMA GEMM epilogue.
// ---------------------------------------------------------------------------

typedef __attribute__((ext_vector_type(8))) short bf16x8;
typedef __attribute__((ext_vector_type(8))) unsigned short u16x8;
typedef __attribute__((ext_vector_type(4))) float f32x4;
typedef unsigned short u16;

#define MPAD 20096   // 20000 padded to multiple of 128

__device__ inline u16 f2b(float f) {
  union { float f; unsigned int u; } x; x.f = f;
  unsigned int r = x.u + 0x7FFFu + ((x.u >> 16) & 1u);   // RNE
  return (u16)(r >> 16);
}
__device__ inline float b2f(u16 u) {
  union { unsigned int u; float f; } x; x.u = ((unsigned int)u) << 16; return x.f;
}

// ----------------------- conversion kernels --------------------------------

// x fp32 [M x K] -> xb bf16 [MPAD x K], pad rows zeroed
__global__ __launch_bounds__(256) void cvt_x(
    const float* __restrict__ in, u16* __restrict__ out, int M, int K) {
  int idx = (blockIdx.x * 256 + threadIdx.x) * 4;
  if (idx >= MPAD * K) return;
  int r = idx / K;
  float4 v = make_float4(0.f, 0.f, 0.f, 0.f);
  if (r < M) v = *reinterpret_cast<const float4*>(&in[idx]);
  ushort4 o;
  o.x = f2b(v.x); o.y = f2b(v.y); o.z = f2b(v.z); o.w = f2b(v.w);
  *reinterpret_cast<ushort4*>(&out[idx]) = o;
}

// W fp32 [K x N] -> WT bf16 [N x K]
__global__ __launch_bounds__(256) void cvt_wT(
    const float* __restrict__ W, u16* __restrict__ WT, int K, int N) {
  int t = blockIdx.x * 256 + threadIdx.x;
  if (t >= K * N) return;
  int n = t / K, k = t - n * K;
  WT[t] = f2b(W[(size_t)k * N + n]);
}

// ----------------------- CSR build -----------------------------------------

__global__ __launch_bounds__(256) void count_deg(
    const int* __restrict__ dst, int* __restrict__ cnt, int E) {
  int e = blockIdx.x * 256 + threadIdx.x;
  if (e < E) atomicAdd(&cnt[dst[e]], 1);
}

__global__ __launch_bounds__(1024) void exscan_kernel(
    const int* __restrict__ in, int* __restrict__ out, int n) {
  __shared__ int buf[2][1024];
  __shared__ int carry;
  if (threadIdx.x == 0) carry = 0;
  __syncthreads();
  for (int base = 0; base < n; base += 1024) {
    int i = base + threadIdx.x;
    int v = (i < n) ? in[i] : 0;
    int cur = 0;
    buf[0][threadIdx.x] = v;
    __syncthreads();
    #pragma unroll
    for (int off = 1; off < 1024; off <<= 1) {
      int val = buf[cur][threadIdx.x];
      if (threadIdx.x >= off) val += buf[cur][threadIdx.x - off];
      buf[cur ^ 1][threadIdx.x] = val;
      cur ^= 1;
      __syncthreads();
    }
    int incl = buf[cur][threadIdx.x];
    if (i < n) out[i] = carry + incl - v;
    __syncthreads();
    if (threadIdx.x == 0) carry += buf[cur][1023];
    __syncthreads();
  }
  if (threadIdx.x == 0) out[n] = carry;
}

__global__ __launch_bounds__(256) void scatter_csr(
    const int* __restrict__ dst, const int* __restrict__ src,
    const float* __restrict__ ew, const int* __restrict__ row_ptr,
    int* __restrict__ cnt, int* __restrict__ csr_src,
    float* __restrict__ csr_w, int E) {
  int e = blockIdx.x * 256 + threadIdx.x;
  if (e >= E) return;
  int d = dst[e];
  int pos = row_ptr[d] + atomicAdd(&cnt[d], 1);
  csr_src[pos] = src[e];
  csr_w[pos] = ew[e];
}

// ----------------------- bf16 MFMA GEMM ------------------------------------
// C[M x Nn] = A[M x K] @ B, BT[Nn x K] given (bf16 row-major both).
// 128x128 tile, BK=64, 4 waves x (64x64). LDS linear + pre-swizzled source.
// ACT: 0=none, 1=tanh.
template <int ACT, bool BIAS, bool OUT_BF16>
__global__ __launch_bounds__(256) void gemm_mfma_bf16(
    const u16* __restrict__ A, const u16* __restrict__ BT,
    const float* __restrict__ bias, void* __restrict__ C,
    int M, int K, int Nn) {
  __shared__ __align__(16) u16 As[128 * 64];
  __shared__ __align__(16) u16 Bs[128 * 64];
  const int tid = threadIdx.x;
  const int lane = tid & 63;
  const int wave = tid >> 6;
  const int lo = lane & 15, hi = lane >> 4;
  const int wr = wave >> 1, wc = wave & 1;
  const int row0 = blockIdx.y * 128;
  const int col0 = blockIdx.x * 128;

  f32x4 acc[4][4] = {};

  for (int kt = 0; kt < K; kt += 64) {
    __syncthreads();
    #pragma unroll
    for (int i = 0; i < 4; ++i) {
      int o = i * 4096 + tid * 16;         // linear byte offset in 16KB tile
      int r = o >> 7;
      int kb = o & 127;
      int ke = (kb >> 1) ^ ((r & 7) << 3); // pre-swizzled element within row
      const u16* ga = &A[(size_t)(row0 + r) * K + kt + ke];
      const u16* gb = &BT[(size_t)(col0 + r) * K + kt + ke];
      __builtin_amdgcn_global_load_lds(
          (const __attribute__((address_space(1))) void*)ga,
          (__attribute__((address_space(3))) void*)&As[o >> 1], 16, 0, 0);
      __builtin_amdgcn_global_load_lds(
          (const __attribute__((address_space(1))) void*)gb,
          (__attribute__((address_space(3))) void*)&Bs[o >> 1], 16, 0, 0);
    }
    __syncthreads();

    #pragma unroll
    for (int ks = 0; ks < 2; ++ks) {
      bf16x8 af[4], bfr[4];
      #pragma unroll
      for (int m = 0; m < 4; ++m) {
        int row = wr * 64 + m * 16 + lo;
        int idx = (row * 64 + ks * 32 + hi * 8) ^ ((row & 7) << 3);
        af[m] = *reinterpret_cast<const bf16x8*>(&As[idx]);
      }
      #pragma unroll
      for (int n = 0; n < 4; ++n) {
        int col = wc * 64 + n * 16 + lo;
        int idx = (col * 64 + ks * 32 + hi * 8) ^ ((col & 7) << 3);
        bfr[n] = *reinterpret_cast<const bf16x8*>(&Bs[idx]);
      }
      #pragma unroll
      for (int m = 0; m < 4; ++m)
        #pragma unroll
        for (int n = 0; n < 4; ++n)
          acc[m][n] = __builtin_amdgcn_mfma_f32_16x16x32_bf16(
              af[m], bfr[n], acc[m][n], 0, 0, 0);
    }
  }

  float bv[4];
  if (BIAS) {
    #pragma unroll
    for (int n = 0; n < 4; ++n) bv[n] = bias[col0 + wc * 64 + n * 16 + lo];
  }

  u16* Cb = (u16*)C;
  float* Cf = (float*)C;
  #pragma unroll
  for (int m = 0; m < 4; ++m) {
    int rbase = row0 + wr * 64 + m * 16 + hi * 4;
    #pragma unroll
    for (int n = 0; n < 4; ++n) {
      int c = col0 + wc * 64 + n * 16 + lo;
      #pragma unroll
      for (int i = 0; i < 4; ++i) {
        float v = acc[m][n][i];
        if (BIAS) v += bv[n];
        if (ACT == 1) v = tanhf(v);
        size_t off = (size_t)(rbase + i) * Nn + c;
        if (OUT_BF16) Cb[off] = f2b(v);
        else Cf[off] = v;
      }
    }
  }
}

// ----------------------- spmm: wave per node, F=512 -------------------------
// out[i][:] = act( sum_p w[p] * H[csr_src[p]][:] (+ bias) ).  H bf16.
// One wave per node; lane handles 8 cols (ushort8). Edge (src,w) staged to
// LDS in chunks of 64 by the wave, consumed as broadcasts.
template <int ACT, bool BIAS, bool OUT_BF16>
__global__ __launch_bounds__(256) void spmm_wave512(
    const int* __restrict__ row_ptr, const int* __restrict__ csr_src,
    const float* __restrict__ csr_w, const u16* __restrict__ H,
    const float* __restrict__ bias, void* __restrict__ out, int N) {
  __shared__ int s_src[4][64];
  __shared__ float s_w[4][64];
  const int wv = threadIdx.x >> 6;
  const int lane = threadIdx.x & 63;
  const int node = blockIdx.x * 4 + wv;
  if (node >= N) return;
  const int c = lane * 8;
  const int beg = row_ptr[node], end = row_ptr[node + 1];

  float a[8] = {};
  for (int p = beg; p < end; p += 64) {
    int cnt = end - p;
    if (cnt > 64) cnt = 64;
    if (lane < cnt) {
      s_src[wv][lane] = csr_src[p + lane];
      s_w[wv][lane] = csr_w[p + lane];
    }
    // wave-synchronous: drain LDS writes so all lanes see the staged edges
    asm volatile("s_waitcnt lgkmcnt(0)" ::: "memory");
    for (int j = 0; j < cnt; ++j) {
      int s = s_src[wv][j];          // LDS broadcast (uniform addr)
      float wt = s_w[wv][j];
      u16x8 hv = *reinterpret_cast<const u16x8*>(&H[(size_t)s * 512 + c]);
      #pragma unroll
      for (int k = 0; k < 8; ++k) a[k] += wt * b2f(hv[k]);
    }
    asm volatile("s_waitcnt lgkmcnt(0) vmcnt(0)" ::: "memory");
  }
  if (BIAS) {
    #pragma unroll
    for (int k = 0; k < 8; ++k) a[k] += bias[c + k];
  }
  if (ACT == 1) {
    #pragma unroll
    for (int k = 0; k < 8; ++k) a[k] = tanhf(a[k]);
  }
  if (OUT_BF16) {
    u16x8 o;
    #pragma unroll
    for (int k = 0; k < 8; ++k) o[k] = f2b(a[k]);
    *reinterpret_cast<u16x8*>(&((u16*)out)[(size_t)node * 512 + c]) = o;
  } else {
    float* op = &((float*)out)[(size_t)node * 512 + c];
    #pragma unroll
    for (int k = 0; k < 8; ++k) op[k] = a[k];
  }
}

// ----------------------- spmm: small F (128) --------------------------------
template <int F, int ACT, bool BIAS, bool OUT_BF16>
__global__ __launch_bounds__(256) void spmm_small(
    const int* __restrict__ row_ptr, const int* __restrict__ csr_src,
    const float* __restrict__ csr_w, const u16* __restrict__ H,
    const float* __restrict__ bias, void* __restrict__ out, int N) {
  constexpr int TPN = F / 8;
  constexpr int NPB = 256 / TPN;
  int sub = threadIdx.x / TPN;
  int ln = threadIdx.x - sub * TPN;
  int node = blockIdx.x * NPB + sub;
  if (node >= N) return;
  int c = ln * 8;
  int beg = row_ptr[node], end = row_ptr[node + 1];
  float a[8] = {};
  for (int p = beg; p < end; ++p) {
    int s = csr_src[p];
    float wt = csr_w[p];
    u16x8 hv = *reinterpret_cast<const u16x8*>(&H[(size_t)s * F + c]);
    #pragma unroll
    for (int k = 0; k < 8; ++k) a[k] += wt * b2f(hv[k]);
  }
  if (BIAS) {
    #pragma unroll
    for (int k = 0; k < 8; ++k) a[k] += bias[c + k];
  }
  if (ACT == 1) {
    #pragma unroll
    for (int k = 0; k < 8; ++k) a[k] = tanhf(a[k]);
  }
  if (OUT_BF16) {
    u16x8 o;
    #pragma unroll
    for (int k = 0; k < 8; ++k) o[k] = f2b(a[k]);
    *reinterpret_cast<u16x8*>(&((u16*)out)[(size_t)node * F + c]) = o;
  } else {
    float* op = &((float*)out)[(size_t)node * F + c];
    #pragma unroll
    for (int k = 0; k < 8; ++k) op[k] = a[k];
  }
}

// ----------------------- fp32 dense head -----------------------------------

#define BM 64
#define BN 64
#define BK 16

template <int ACT>   // 0=none, 1=tanh, 2=relu
__global__ __launch_bounds__(256) void gemm_bias_act(
    const float* __restrict__ A, const float* __restrict__ B,
    const float* __restrict__ bias, float* __restrict__ C,
    int M, int K, int N) {
  __shared__ float As[BK][BM + 1];
  __shared__ float Bs[BK][BN + 1];
  const int tx = threadIdx.x & 15;
  const int ty = threadIdx.x >> 4;
  const int row0 = blockIdx.y * BM;
  const int col0 = blockIdx.x * BN;
  float acc[4][4] = {};
  for (int k0 = 0; k0 < K; k0 += BK) {
    #pragma unroll
    for (int i = threadIdx.x; i < BM * BK; i += 256) {
      int r = i >> 4, c = i & 15;
      float v = 0.f;
      if (row0 + r < M && k0 + c < K) v = A[(size_t)(row0 + r) * K + k0 + c];
      As[c][r] = v;
    }
    #pragma unroll
    for (int i = threadIdx.x; i < BK * BN; i += 256) {
      int r = i >> 6, c = i & 63;
      float v = 0.f;
      if (k0 + r < K && col0 + c < N) v = B[(size_t)(k0 + r) * N + col0 + c];
      Bs[r][c] = v;
    }
    __syncthreads();
    #pragma unroll
    for (int kk = 0; kk < BK; ++kk) {
      float a[4], b[4];
      #pragma unroll
      for (int i = 0; i < 4; ++i) a[i] = As[kk][ty * 4 + i];
      #pragma unroll
      for (int j = 0; j < 4; ++j) b[j] = Bs[kk][tx * 4 + j];
      #pragma unroll
      for (int i = 0; i < 4; ++i)
        #pragma unroll
        for (int j = 0; j < 4; ++j)
          acc[i][j] += a[i] * b[j];
    }
    __syncthreads();
  }
  #pragma unroll
  for (int i = 0; i < 4; ++i) {
    int r = row0 + ty * 4 + i;
    if (r >= M) continue;
    #pragma unroll
    for (int j = 0; j < 4; ++j) {
      int c = col0 + tx * 4 + j;
      if (c >= N) continue;
      float v = acc[i][j];
      if (bias) v += bias[c];
      if (ACT == 1) v = tanhf(v);
      else if (ACT == 2) v = fmaxf(v, 0.f);
      C[(size_t)r * N + c] = v;
    }
  }
}

__global__ __launch_bounds__(256) void last_layer(
    const float* __restrict__ D2v, const float* __restrict__ W,
    const float* __restrict__ b, float* __restrict__ out, int M, int K) {
  int r = blockIdx.x * 256 + threadIdx.x;
  if (r >= M) return;
  float s = b[0];
  const float* row = &D2v[(size_t)r * K];
  #pragma unroll 4
  for (int k = 0; k < K; ++k) s += row[k] * W[k];
  out[r] = s;
}

// ---------------------------------------------------------------------------

extern "C" void kernel_launch(void* const* d_in, const int* in_sizes, int n_in,
                              void* d_out, int out_size, void* d_ws, size_t ws_size,
                              hipStream_t stream) {
  const int N = 20000, E = 320000;
  const int F_IN = 512, H1 = 1024, H2 = 512, F_OUT = 128;
  const int D1 = 152, D2 = 48;

  const float* x    = (const float*)d_in[0];
  const int*   src  = (const int*)d_in[1];
  const int*   dst  = (const int*)d_in[2];
  const float* ew   = (const float*)d_in[3];
  const float* W1   = (const float*)d_in[4];
  const float* b1   = (const float*)d_in[5];
  const float* W2   = (const float*)d_in[6];
  const float* b2   = (const float*)d_in[7];
  const float* W3   = (const float*)d_in[8];
  const float* b3   = (const float*)d_in[9];
  const float* Wd1  = (const float*)d_in[10];
  const float* bd1  = (const float*)d_in[11];
  const float* Wd2  = (const float*)d_in[12];
  const float* bd2  = (const float*)d_in[13];
  const float* Wd3  = (const float*)d_in[14];
  const float* bd3  = (const float*)d_in[15];
  float* out = (float*)d_out;

  // ---- workspace (bump alloc, 256B aligned) ----
  size_t off = 0;
  auto alloc = [&](size_t bytes) {
    void* p = (char*)d_ws + off;
    off += (bytes + 255) & ~(size_t)255;
    return p;
  };
  u16* xb    = (u16*)alloc((size_t)MPAD * F_IN * 2);   // x bf16; later t2
  u16* ax    = (u16*)alloc((size_t)MPAD * F_IN * 2);   // A@x;   later h2
  u16* h1    = (u16*)alloc((size_t)MPAD * H1 * 2);     // h1; later t3,g,d1,d2
  u16* w1t   = (u16*)alloc((size_t)H1 * F_IN * 2);
  u16* w2t   = (u16*)alloc((size_t)H2 * H1 * 2);
  u16* w3t   = (u16*)alloc((size_t)F_OUT * H2 * 2);
  int* row_ptr = (int*)alloc((size_t)(N + 1) * 4);
  int* cnt     = (int*)alloc((size_t)N * 4);
  int* csr_src = (int*)alloc((size_t)E * 4);
  float* csr_w = (float*)alloc((size_t)E * 4);

  u16* t2 = xb;                                   // MPAD x 512
  u16* h2 = ax;                                   // MPAD x 512
  u16* t3 = h1;                                   // MPAD x 128 (h1 dead)
  float* g  = (float*)((char*)h1 + 5300224);      // 20000 x 128 fp32
  float* d1 = (float*)((char*)h1 + 16777216);     // 20000 x 152 fp32
  float* d2 = (float*)((char*)h1 + 30408704);     // 20000 x 48 fp32

  auto cdiv = [](int a, int b) { return (a + b - 1) / b; };

  // ---- conversions ----
  cvt_x<<<cdiv(MPAD * F_IN / 4, 256), 256, 0, stream>>>(x, xb, N, F_IN);
  cvt_wT<<<cdiv(F_IN * H1, 256), 256, 0, stream>>>(W1, w1t, F_IN, H1);
  cvt_wT<<<cdiv(H1 * H2, 256), 256, 0, stream>>>(W2, w2t, H1, H2);
  cvt_wT<<<cdiv(H2 * F_OUT, 256), 256, 0, stream>>>(W3, w3t, H2, F_OUT);

  // zero pad rows of ax (rows 20000..20095) so GEMM1 reads defined zeros;
  // this region is reused as h2 whose pad rows then stay zero for GEMM3.
  hipMemsetAsync(ax + (size_t)N * F_IN, 0, (size_t)(MPAD - N) * F_IN * 2, stream);

  // ---- CSR build ----
  hipMemsetAsync(cnt, 0, (size_t)N * 4, stream);
  count_deg<<<cdiv(E, 256), 256, 0, stream>>>(dst, cnt, E);
  exscan_kernel<<<1, 1024, 0, stream>>>(cnt, row_ptr, N);
  hipMemsetAsync(cnt, 0, (size_t)N * 4, stream);
  scatter_csr<<<cdiv(E, 256), 256, 0, stream>>>(dst, src, ew, row_ptr, cnt,
                                                csr_src, csr_w, E);

  // ---- layer 1 (reordered): ax = A@x ; h1 = tanh(ax@W1 + b1) ----
  spmm_wave512<0, false, true><<<cdiv(N, 4), 256, 0, stream>>>(
      row_ptr, csr_src, csr_w, xb, nullptr, ax, N);
  {
    dim3 gr(H1 / 128, MPAD / 128);
    gemm_mfma_bf16<1, true, true><<<gr, 256, 0, stream>>>(ax, w1t, b1, h1,
                                                          MPAD, F_IN, H1);
  }

  // ---- layer 2: t2 = h1@W2 ; h2 = tanh(A@t2 + b2) ----
  {
    dim3 gr(H2 / 128, MPAD / 128);
    gemm_mfma_bf16<0, false, true><<<gr, 256, 0, stream>>>(h1, w2t, nullptr,
                                                           t2, MPAD, H1, H2);
  }
  spmm_wave512<1, true, true><<<cdiv(N, 4), 256, 0, stream>>>(
      row_ptr, csr_src, csr_w, t2, b2, h2, N);

  // ---- layer 3: t3 = h2@W3 ; g = A@t3 + b3 (fp32) ----
  {
    dim3 gr(F_OUT / 128, MPAD / 128);
    gemm_mfma_bf16<0, false, true><<<gr, 256, 0, stream>>>(h2, w3t, nullptr,
                                                           t3, MPAD, H2, F_OUT);
  }
  spmm_small<128, 0, true, false><<<cdiv(N, 16), 256, 0, stream>>>(
      row_ptr, csr_src, csr_w, t3, b3, g, N);

  // ---- dense head (fp32) ----
  {
    dim3 gr(cdiv(D1, BN), cdiv(N, BM));
    gemm_bias_act<2><<<gr, 256, 0, stream>>>(g, Wd1, bd1, d1, N, F_OUT, D1);
  }
  {
    dim3 gr(cdiv(D2, BN), cdiv(N, BM));
    gemm_bias_act<2><<<gr, 256, 0, stream>>>(d1, Wd2, bd2, d2, N, D1, D2);
  }
  last_layer<<<cdiv(N, 256), 256, 0, stream>>>(d2, Wd3, bd3, out, N, D2);
}

// Round 6
// 299.104 us; speedup vs baseline: 27.0416x; 1.2360x over previous
//
#include <hip/hip_runtime.h>
#include <hip/hip_bf16.h>

// ---------------------------------------------------------------------------
// GCN (3x GCNConv) + dense head, bf16 MFMA everywhere it matters.
// Round 6: counted-vmcnt double-buffered GEMM (T3+T4), setprio (T5),
// bijective XCD swizzle (T1/m204), dense head in MFMA with zero-padded
// widths, wave-shuffle exscan, tiled weight transpose, unroll-4 spmm.
// ---------------------------------------------------------------------------

typedef __attribute__((ext_vector_type(8))) short bf16x8;
typedef __attribute__((ext_vector_type(8))) unsigned short u16x8;
typedef __attribute__((ext_vector_type(4))) float f32x4;
typedef unsigned short u16;

#define MPAD 20096   // 20000 padded to multiple of 128

__device__ inline u16 f2b(float f) {
  union { float f; unsigned int u; } x; x.f = f;
  unsigned int r = x.u + 0x7FFFu + ((x.u >> 16) & 1u);   // RNE
  return (u16)(r >> 16);
}
__device__ inline float b2f(u16 u) {
  union { unsigned int u; float f; } x; x.u = ((unsigned int)u) << 16; return x.f;
}

// ----------------------- conversion kernels --------------------------------

// x fp32 [M x K] -> xb bf16 [MPAD x K] (pad rows left as-is; row-local garbage)
__global__ __launch_bounds__(256) void cvt_x(
    const float* __restrict__ in, u16* __restrict__ out, int M, int K) {
  int idx = (blockIdx.x * 256 + threadIdx.x) * 4;
  if (idx >= M * K) return;
  float4 v = *reinterpret_cast<const float4*>(&in[idx]);
  ushort4 o;
  o.x = f2b(v.x); o.y = f2b(v.y); o.z = f2b(v.z); o.w = f2b(v.w);
  *reinterpret_cast<ushort4*>(&out[idx]) = o;
}

// W [K x N] fp32 -> WT [NPAD x KPAD] bf16, zero-filled outside KxN.
// grid(NPAD/32, KPAD/32), 256 threads (32x8), coalesced both sides.
__global__ __launch_bounds__(256) void cvt_wT_tile(
    const float* __restrict__ W, u16* __restrict__ WT,
    int K, int N, int KPAD, int NPAD) {
  __shared__ float tile[32][33];
  const int kb = blockIdx.y * 32, nb = blockIdx.x * 32;
  const int tx = threadIdx.x & 31, ty = threadIdx.x >> 5;
  #pragma unroll
  for (int i = 0; i < 4; ++i) {
    int k = kb + ty + i * 8, n = nb + tx;
    tile[ty + i * 8][tx] = (k < K && n < N) ? W[(size_t)k * N + n] : 0.f;
  }
  __syncthreads();
  #pragma unroll
  for (int i = 0; i < 4; ++i) {
    int n = nb + ty + i * 8, k = kb + tx;
    WT[(size_t)n * KPAD + k] = f2b(tile[tx][ty + i * 8]);
  }
}

__global__ __launch_bounds__(256) void pad_bias(
    const float* __restrict__ b, float* __restrict__ bp, int n, int npad) {
  int i = blockIdx.x * 256 + threadIdx.x;
  if (i < npad) bp[i] = (i < n) ? b[i] : 0.f;
}

// ----------------------- CSR build -----------------------------------------

__global__ __launch_bounds__(256) void count_deg(
    const int* __restrict__ dst, int* __restrict__ cnt, int E) {
  int e = blockIdx.x * 256 + threadIdx.x;
  if (e < E) atomicAdd(&cnt[dst[e]], 1);
}

// single-block exclusive scan, wave-shuffle based. 1024 threads = 16 waves.
__global__ __launch_bounds__(1024) void exscan_kernel(
    const int* __restrict__ in, int* __restrict__ out, int n) {
  __shared__ int wsum[16];
  __shared__ int carry_s;
  if (threadIdx.x == 0) carry_s = 0;
  __syncthreads();
  const int lane = threadIdx.x & 63, wv = threadIdx.x >> 6;
  for (int base = 0; base < n; base += 1024) {
    int i = base + threadIdx.x;
    int v = (i < n) ? in[i] : 0;
    int s = v;                         // inclusive scan within wave
    #pragma unroll
    for (int off = 1; off < 64; off <<= 1) {
      int t = __shfl_up(s, off, 64);
      if (lane >= off) s += t;
    }
    if (lane == 63) wsum[wv] = s;
    __syncthreads();
    if (wv == 0 && lane < 16) {        // scan the 16 wave totals
      int t = wsum[lane];
      #pragma unroll
      for (int off = 1; off < 16; off <<= 1) {
        int u = __shfl_up(t, off, 64);
        if (lane >= off) t += u;
      }
      wsum[lane] = t;                  // inclusive
    }
    __syncthreads();
    int waveoff = (wv == 0) ? 0 : wsum[wv - 1];
    int res = carry_s + waveoff + s - v;   // exclusive
    if (i < n) out[i] = res;
    __syncthreads();
    if (threadIdx.x == 0) carry_s += wsum[15];
    __syncthreads();
  }
  if (threadIdx.x == 0) out[n] = carry_s;
}

__global__ __launch_bounds__(256) void scatter_csr(
    const int* __restrict__ dst, const int* __restrict__ src,
    const float* __restrict__ ew, const int* __restrict__ row_ptr,
    int* __restrict__ cnt, int* __restrict__ csr_src,
    float* __restrict__ csr_w, int E) {
  int e = blockIdx.x * 256 + threadIdx.x;
  if (e >= E) return;
  int d = dst[e];
  int pos = row_ptr[d] + atomicAdd(&cnt[d], 1);
  csr_src[pos] = src[e];
  csr_w[pos] = ew[e];
}

// ----------------------- bf16 MFMA GEMM, counted-vmcnt 2-phase --------------
// C[M x Nn] = A[M x K] @ B, BT[Nn x K] given (bf16 row-major).
// M,Nn multiples of 128; K multiple of 64 (nk = K/64 >= 2).
// Double-buffered LDS; STAGE(t+2) overlaps MFMA(t); vmcnt(8) never drains.
// ACT: 0=none, 1=tanh, 2=relu.
template <int ACT, bool BIAS, bool OUT_BF16>
__global__ __launch_bounds__(256) void gemm_mfma_db(
    const u16* __restrict__ A, const u16* __restrict__ BT,
    const float* __restrict__ bias, void* __restrict__ C,
    int M, int K, int Nn) {
  __shared__ __align__(16) u16 As[2][128 * 64];
  __shared__ __align__(16) u16 Bs[2][128 * 64];
  const int tid = threadIdx.x;
  const int lane = tid & 63;
  const int wave = tid >> 6;
  const int lo = lane & 15, hi = lane >> 4;
  const int wr = wave >> 1, wc = wave & 1;

  // bijective XCD swizzle (m204): contiguous grid chunks per XCD
  const int gx = gridDim.x;
  const int nwg = gx * gridDim.y;
  const int wg = blockIdx.y * gx + blockIdx.x;
  const int q = nwg >> 3, r = nwg & 7;
  const int xcd = wg & 7, sidx = wg >> 3;
  const int swz = (xcd < r ? xcd * (q + 1) : r * (q + 1) + (xcd - r) * q) + sidx;
  const int row0 = (swz / gx) * 128;
  const int col0 = (swz % gx) * 128;

  // staging geometry: thread covers 4 chunks of 16B; pre-swizzled source
  int sr[4], ske[4];
  #pragma unroll
  for (int i = 0; i < 4; ++i) {
    int o = i * 4096 + tid * 16;
    sr[i] = o >> 7;
    ske[i] = ((o & 127) >> 1) ^ ((sr[i] & 7) << 3);
  }

  const int nk = K >> 6;
  f32x4 acc[4][4] = {};

  auto STAGE = [&](int buf, int kt) {
    const int ko = kt << 6;
    #pragma unroll
    for (int i = 0; i < 4; ++i) {
      int o = i * 4096 + tid * 16;
      const u16* ga = &A[(size_t)(row0 + sr[i]) * K + ko + ske[i]];
      const u16* gb = &BT[(size_t)(col0 + sr[i]) * K + ko + ske[i]];
      __builtin_amdgcn_global_load_lds(
          (const __attribute__((address_space(1))) void*)ga,
          (__attribute__((address_space(3))) void*)&As[buf][o >> 1], 16, 0, 0);
      __builtin_amdgcn_global_load_lds(
          (const __attribute__((address_space(1))) void*)gb,
          (__attribute__((address_space(3))) void*)&Bs[buf][o >> 1], 16, 0, 0);
    }
  };

  STAGE(0, 0);
  STAGE(1, 1);
  asm volatile("s_waitcnt vmcnt(8)" ::: "memory");   // buf0's 8 landed
  __builtin_amdgcn_s_barrier();

  for (int kt = 0; kt < nk; ++kt) {
    const int cur = kt & 1;
    bf16x8 af[2][4], bfr[2][4];
    #pragma unroll
    for (int ks = 0; ks < 2; ++ks) {
      #pragma unroll
      for (int m = 0; m < 4; ++m) {
        int row = wr * 64 + m * 16 + lo;
        int idx = (row * 64 + ks * 32 + hi * 8) ^ ((row & 7) << 3);
        af[ks][m] = *reinterpret_cast<const bf16x8*>(&As[cur][idx]);
      }
      #pragma unroll
      for (int n = 0; n < 4; ++n) {
        int col = wc * 64 + n * 16 + lo;
        int idx = (col * 64 + ks * 32 + hi * 8) ^ ((col & 7) << 3);
        bfr[ks][n] = *reinterpret_cast<const bf16x8*>(&Bs[cur][idx]);
      }
    }
    asm volatile("s_waitcnt lgkmcnt(0)" ::: "memory");  // reads pulled to regs
    __builtin_amdgcn_sched_barrier(0);                  // rule 18
    __builtin_amdgcn_s_barrier();                       // all waves done w/ cur
    if (kt + 2 < nk) STAGE(cur, kt + 2);                // refill cur (async)
    __builtin_amdgcn_s_setprio(1);
    #pragma unroll
    for (int ks = 0; ks < 2; ++ks)
      #pragma unroll
      for (int m = 0; m < 4; ++m)
        #pragma unroll
        for (int n = 0; n < 4; ++n)
          acc[m][n] = __builtin_amdgcn_mfma_f32_16x16x32_bf16(
              af[ks][m], bfr[ks][n], acc[m][n], 0, 0, 0);
    __builtin_amdgcn_s_setprio(0);
    if (kt + 2 < nk) {
      asm volatile("s_waitcnt vmcnt(8)" ::: "memory");  // next buf landed
    } else if (kt + 1 < nk) {
      asm volatile("s_waitcnt vmcnt(0)" ::: "memory");  // last prefetch landed
    }
    __builtin_amdgcn_s_barrier();
  }

  float bv[4];
  if (BIAS) {
    #pragma unroll
    for (int n = 0; n < 4; ++n) bv[n] = bias[col0 + wc * 64 + n * 16 + lo];
  }

  u16* Cb = (u16*)C;
  float* Cf = (float*)C;
  #pragma unroll
  for (int m = 0; m < 4; ++m) {
    int rbase = row0 + wr * 64 + m * 16 + hi * 4;
    #pragma unroll
    for (int n = 0; n < 4; ++n) {
      int c = col0 + wc * 64 + n * 16 + lo;
      #pragma unroll
      for (int i = 0; i < 4; ++i) {
        float v = acc[m][n][i];
        if (BIAS) v += bv[n];
        if (ACT == 1) v = tanhf(v);
        else if (ACT == 2) v = fmaxf(v, 0.f);
        size_t off2 = (size_t)(rbase + i) * Nn + c;
        if (OUT_BF16) Cb[off2] = f2b(v);
        else Cf[off2] = v;
      }
    }
  }
}

// ----------------------- spmm: wave per node, F=512 -------------------------
template <int ACT, bool BIAS, bool OUT_BF16>
__global__ __launch_bounds__(256) void spmm_wave512(
    const int* __restrict__ row_ptr, const int* __restrict__ csr_src,
    const float* __restrict__ csr_w, const u16* __restrict__ H,
    const float* __restrict__ bias, void* __restrict__ out, int N) {
  __shared__ int s_src[4][64];
  __shared__ float s_w[4][64];
  const int wv = threadIdx.x >> 6;
  const int lane = threadIdx.x & 63;
  const int node = blockIdx.x * 4 + wv;
  if (node >= N) return;
  const int c = lane * 8;
  const int beg = row_ptr[node], end = row_ptr[node + 1];

  float a[8] = {};
  for (int p = beg; p < end; p += 64) {
    int cnt = end - p;
    if (cnt > 64) cnt = 64;
    if (lane < cnt) {
      s_src[wv][lane] = csr_src[p + lane];
      s_w[wv][lane] = csr_w[p + lane];
    }
    asm volatile("s_waitcnt lgkmcnt(0)" ::: "memory");
    int j = 0;
    for (; j + 3 < cnt; j += 4) {
      int s0 = s_src[wv][j], s1 = s_src[wv][j + 1];
      int s2 = s_src[wv][j + 2], s3 = s_src[wv][j + 3];
      float w0 = s_w[wv][j], w1 = s_w[wv][j + 1];
      float w2 = s_w[wv][j + 2], w3 = s_w[wv][j + 3];
      u16x8 h0 = *reinterpret_cast<const u16x8*>(&H[(size_t)s0 * 512 + c]);
      u16x8 h1 = *reinterpret_cast<const u16x8*>(&H[(size_t)s1 * 512 + c]);
      u16x8 h2 = *reinterpret_cast<const u16x8*>(&H[(size_t)s2 * 512 + c]);
      u16x8 h3 = *reinterpret_cast<const u16x8*>(&H[(size_t)s3 * 512 + c]);
      #pragma unroll
      for (int k = 0; k < 8; ++k)
        a[k] += w0 * b2f(h0[k]) + w1 * b2f(h1[k]) +
                w2 * b2f(h2[k]) + w3 * b2f(h3[k]);
    }
    for (; j < cnt; ++j) {
      int s = s_src[wv][j];
      float wt = s_w[wv][j];
      u16x8 hv = *reinterpret_cast<const u16x8*>(&H[(size_t)s * 512 + c]);
      #pragma unroll
      for (int k = 0; k < 8; ++k) a[k] += wt * b2f(hv[k]);
    }
    asm volatile("s_waitcnt lgkmcnt(0)" ::: "memory");
  }
  if (BIAS) {
    #pragma unroll
    for (int k = 0; k < 8; ++k) a[k] += bias[c + k];
  }
  if (ACT == 1) {
    #pragma unroll
    for (int k = 0; k < 8; ++k) a[k] = tanhf(a[k]);
  }
  if (OUT_BF16) {
    u16x8 o;
    #pragma unroll
    for (int k = 0; k < 8; ++k) o[k] = f2b(a[k]);
    *reinterpret_cast<u16x8*>(&((u16*)out)[(size_t)node * 512 + c]) = o;
  } else {
    float* op = &((float*)out)[(size_t)node * 512 + c];
    #pragma unroll
    for (int k = 0; k < 8; ++k) op[k] = a[k];
  }
}

// ----------------------- spmm: small F (128) --------------------------------
template <int F, int ACT, bool BIAS, bool OUT_BF16>
__global__ __launch_bounds__(256) void spmm_small(
    const int* __restrict__ row_ptr, const int* __restrict__ csr_src,
    const float* __restrict__ csr_w, const u16* __restrict__ H,
    const float* __restrict__ bias, void* __restrict__ out, int N) {
  constexpr int TPN = F / 8;
  constexpr int NPB = 256 / TPN;
  int sub = threadIdx.x / TPN;
  int ln = threadIdx.x - sub * TPN;
  int node = blockIdx.x * NPB + sub;
  if (node >= N) return;
  int c = ln * 8;
  int beg = row_ptr[node], end = row_ptr[node + 1];
  float a[8] = {};
  for (int p = beg; p < end; ++p) {
    int s = csr_src[p];
    float wt = csr_w[p];
    u16x8 hv = *reinterpret_cast<const u16x8*>(&H[(size_t)s * F + c]);
    #pragma unroll
    for (int k = 0; k < 8; ++k) a[k] += wt * b2f(hv[k]);
  }
  if (BIAS) {
    #pragma unroll
    for (int k = 0; k < 8; ++k) a[k] += bias[c + k];
  }
  if (ACT == 1) {
    #pragma unroll
    for (int k = 0; k < 8; ++k) a[k] = tanhf(a[k]);
  }
  if (OUT_BF16) {
    u16x8 o;
    #pragma unroll
    for (int k = 0; k < 8; ++k) o[k] = f2b(a[k]);
    *reinterpret_cast<u16x8*>(&((u16*)out)[(size_t)node * F + c]) = o;
  } else {
    float* op = &((float*)out)[(size_t)node * F + c];
    #pragma unroll
    for (int k = 0; k < 8; ++k) op[k] = a[k];
  }
}

// out[r] = dot(D2row(bf16)[:K], W[:K]) + b[0]
__global__ __launch_bounds__(256) void last_layer_bf16(
    const u16* __restrict__ D2v, const float* __restrict__ W,
    const float* __restrict__ b, float* __restrict__ out,
    int M, int K, int ld) {
  int rr = blockIdx.x * 256 + threadIdx.x;
  if (rr >= M) return;
  float s = b[0];
  const u16* row = &D2v[(size_t)rr * ld];
  #pragma unroll 8
  for (int k = 0; k < 48; ++k) s += b2f(row[k]) * W[k];
  out[rr] = s;
}

// ---------------------------------------------------------------------------

extern "C" void kernel_launch(void* const* d_in, const int* in_sizes, int n_in,
                              void* d_out, int out_size, void* d_ws, size_t ws_size,
                              hipStream_t stream) {
  const int N = 20000, E = 320000;
  const int F_IN = 512, H1 = 1024, H2 = 512, F_OUT = 128;
  const int D1 = 152, D2 = 48;
  const int D1P = 256, D2P = 128;   // padded dense widths

  const float* x    = (const float*)d_in[0];
  const int*   src  = (const int*)d_in[1];
  const int*   dst  = (const int*)d_in[2];
  const float* ew   = (const float*)d_in[3];
  const float* W1   = (const float*)d_in[4];
  const float* b1   = (const float*)d_in[5];
  const float* W2   = (const float*)d_in[6];
  const float* b2   = (const float*)d_in[7];
  const float* W3   = (const float*)d_in[8];
  const float* b3   = (const float*)d_in[9];
  const float* Wd1  = (const float*)d_in[10];
  const float* bd1  = (const float*)d_in[11];
  const float* Wd2  = (const float*)d_in[12];
  const float* bd2  = (const float*)d_in[13];
  const float* Wd3  = (const float*)d_in[14];
  const float* bd3  = (const float*)d_in[15];
  float* out = (float*)d_out;

  // ---- workspace (bump alloc, 256B aligned) ----
  size_t off = 0;
  auto alloc = [&](size_t bytes) {
    void* p = (char*)d_ws + off;
    off += (bytes + 255) & ~(size_t)255;
    return p;
  };
  u16* xb   = (u16*)alloc((size_t)MPAD * F_IN * 2);    // x bf16; later t2
  u16* ax   = (u16*)alloc((size_t)MPAD * F_IN * 2);    // A@x;   later h2
  u16* h1   = (u16*)alloc((size_t)MPAD * H1 * 2);      // h1 (also t3..d2 region)
  u16* w1t  = (u16*)alloc((size_t)H1 * F_IN * 2);
  u16* w2t  = (u16*)alloc((size_t)H2 * H1 * 2);
  u16* w3t  = (u16*)alloc((size_t)F_OUT * H2 * 2);
  u16* wd1t = (u16*)alloc((size_t)D1P * F_OUT * 2);    // [256 x 128]
  u16* wd2t = (u16*)alloc((size_t)D2P * D1P * 2);      // [128 x 256]
  float* bd1p = (float*)alloc((size_t)D1P * 4);
  float* bd2p = (float*)alloc((size_t)D2P * 4);
  int* row_ptr = (int*)alloc((size_t)(N + 1) * 4);
  int* cnt     = (int*)alloc((size_t)N * 4);
  int* csr_src = (int*)alloc((size_t)E * 4);
  float* csr_w = (float*)alloc((size_t)E * 4);

  u16* t2 = xb;                                  // MPAD x 512
  u16* h2 = ax;                                  // MPAD x 512
  // sub-region of h1 (41 MB): t3, gb, d1, d2 disjoint
  u16* t3 = h1;                                  // MPAD x 128
  u16* gb = t3 + (size_t)MPAD * F_OUT;           // MPAD x 128
  u16* d1 = gb + (size_t)MPAD * F_OUT;           // MPAD x 256
  u16* d2 = d1 + (size_t)MPAD * D1P;             // MPAD x 128

  auto cdiv = [](int a, int b) { return (a + b - 1) / b; };

  // ---- conversions ----
  cvt_x<<<cdiv(N * F_IN / 4, 256), 256, 0, stream>>>(x, xb, N, F_IN);
  cvt_wT_tile<<<dim3(H1 / 32, F_IN / 32), 256, 0, stream>>>(W1, w1t, F_IN, H1, F_IN, H1);
  cvt_wT_tile<<<dim3(H2 / 32, H1 / 32), 256, 0, stream>>>(W2, w2t, H1, H2, H1, H2);
  cvt_wT_tile<<<dim3(F_OUT / 32, H2 / 32), 256, 0, stream>>>(W3, w3t, H2, F_OUT, H2, F_OUT);
  cvt_wT_tile<<<dim3(D1P / 32, F_OUT / 32), 256, 0, stream>>>(Wd1, wd1t, F_OUT, D1, F_OUT, D1P);
  cvt_wT_tile<<<dim3(D2P / 32, D1P / 32), 256, 0, stream>>>(Wd2, wd2t, D1, D2, D1P, D2P);
  pad_bias<<<1, 256, 0, stream>>>(bd1, bd1p, D1, D1P);
  pad_bias<<<1, 256, 0, stream>>>(bd2, bd2p, D2, D2P);

  // ---- CSR build ----
  hipMemsetAsync(cnt, 0, (size_t)N * 4, stream);
  count_deg<<<cdiv(E, 256), 256, 0, stream>>>(dst, cnt, E);
  exscan_kernel<<<1, 1024, 0, stream>>>(cnt, row_ptr, N);
  hipMemsetAsync(cnt, 0, (size_t)N * 4, stream);
  scatter_csr<<<cdiv(E, 256), 256, 0, stream>>>(dst, src, ew, row_ptr, cnt,
                                                csr_src, csr_w, E);

  // ---- layer 1 (reordered): ax = A@x ; h1 = tanh(ax@W1 + b1) ----
  spmm_wave512<0, false, true><<<cdiv(N, 4), 256, 0, stream>>>(
      row_ptr, csr_src, csr_w, xb, nullptr, ax, N);
  gemm_mfma_db<1, true, true><<<dim3(H1 / 128, MPAD / 128), 256, 0, stream>>>(
      ax, w1t, b1, h1, MPAD, F_IN, H1);

  // ---- layer 2: t2 = h1@W2 ; h2 = tanh(A@t2 + b2) ----
  gemm_mfma_db<0, false, true><<<dim3(H2 / 128, MPAD / 128), 256, 0, stream>>>(
      h1, w2t, nullptr, t2, MPAD, H1, H2);
  spmm_wave512<1, true, true><<<cdiv(N, 4), 256, 0, stream>>>(
      row_ptr, csr_src, csr_w, t2, b2, h2, N);

  // ---- layer 3: t3 = h2@W3 ; gb = A@t3 + b3 (bf16) ----
  gemm_mfma_db<0, false, true><<<dim3(F_OUT / 128, MPAD / 128), 256, 0, stream>>>(
      h2, w3t, nullptr, t3, MPAD, H2, F_OUT);
  spmm_small<128, 0, true, true><<<cdiv(N, 16), 256, 0, stream>>>(
      row_ptr, csr_src, csr_w, t3, b3, gb, N);

  // ---- dense head (bf16 MFMA, padded widths; pad cols compute exact 0) ----
  gemm_mfma_db<2, true, true><<<dim3(D1P / 128, MPAD / 128), 256, 0, stream>>>(
      gb, wd1t, bd1p, d1, MPAD, F_OUT, D1P);
  gemm_mfma_db<2, true, true><<<dim3(D2P / 128, MPAD / 128), 256, 0, stream>>>(
      d1, wd2t, bd2p, d2, MPAD, D1P, D2P);
  last_layer_bf16<<<cdiv(N, 256), 256, 0, stream>>>(d2, Wd3, bd3, out, N, D2, D2P);
}